// Round 11
// baseline (781.787 us; speedup 1.0000x reference)
//
#include <hip/hip_runtime.h>
#include <math.h>

typedef __bf16 bf16_t;
typedef __attribute__((ext_vector_type(8))) __bf16 bf16x8;
typedef __attribute__((ext_vector_type(4))) __bf16 bf16x4;
typedef __attribute__((ext_vector_type(4))) float f32x4;

#define MFMA16(a,b,c) __builtin_amdgcn_mfma_f32_16x16x32_bf16((a),(b),(c),0,0,0)

// async global->LDS, 16B per lane, LDS dest = base + lane*16 (wave-uniform base)
__device__ __forceinline__ void gload_lds16(const bf16_t* g, bf16_t* l) {
  __builtin_amdgcn_global_load_lds(
      (const __attribute__((address_space(1))) unsigned int*)g,
      (__attribute__((address_space(3))) unsigned int*)l, 16, 0, 0);
}

// ---------------- prep: fp32 -> bf16 conversions ----------------
__global__ __launch_bounds__(256) void k_cvt4(const float* __restrict__ x,
                                              bf16_t* __restrict__ o, int n4) {
  int i = blockIdx.x * 256 + threadIdx.x;
  if (i >= n4) return;
  f32x4 v = *(const f32x4*)(x + (size_t)i * 4);
  bf16x4 b;
  b[0] = (bf16_t)v[0]; b[1] = (bf16_t)v[1]; b[2] = (bf16_t)v[2]; b[3] = (bf16_t)v[3];
  *(bf16x4*)(o + (size_t)i * 4) = b;
}

// builds: w_in_b[256*128], wqkvs_b[3][1024][256] (q|k|v|s rows), bqkvs[3][1024],
//         wnode_b[1024][256] = [Wec1_L | Wec1_R | Wpp1_L | Wpp1_R] rows,
//         bnode[1024] = [bec1 | 0 | bpp1 | 0]
__global__ __launch_bounds__(256) void k_prep_w(
    const float* __restrict__ W_in,
    const float* __restrict__ Wq, const float* __restrict__ Wk,
    const float* __restrict__ Wv, const float* __restrict__ Ws,
    const float* __restrict__ bq, const float* __restrict__ bk,
    const float* __restrict__ bv, const float* __restrict__ bs,
    const float* __restrict__ Wec1, const float* __restrict__ Wpp1,
    const float* __restrict__ bec1, const float* __restrict__ bpp1,
    bf16_t* __restrict__ w_in_b, bf16_t* __restrict__ wqkvs_b,
    float* __restrict__ bqkvs, bf16_t* __restrict__ wnode_b,
    float* __restrict__ bnode) {
  int i = blockIdx.x * 256 + threadIdx.x;
  const int S0 = 256 * 128, S1 = 3 * 1024 * 256, S2 = 1024 * 256, S3 = 3 * 1024, S4 = 1024;
  if (i < S0) { w_in_b[i] = (bf16_t)W_in[i]; return; }
  i -= S0;
  if (i < S1) {
    int l = i / (1024 * 256), rem = i % (1024 * 256);
    int row = rem >> 8, col = rem & 255;
    const float* srcp = (row < 256) ? Wq : (row < 512) ? Wk : (row < 768) ? Wv : Ws;
    wqkvs_b[i] = (bf16_t)srcp[((size_t)l * 256 + (row & 255)) * 256 + col];
    return;
  }
  i -= S1;
  if (i < S2) {
    int row = i >> 8, col = i & 255;
    float v;
    if (row < 256)       v = Wec1[row * 512 + col];
    else if (row < 512)  v = Wec1[(row - 256) * 512 + 256 + col];
    else if (row < 768)  v = Wpp1[(row - 512) * 512 + col];
    else                 v = Wpp1[(row - 768) * 512 + 256 + col];
    wnode_b[i] = (bf16_t)v;
    return;
  }
  i -= S2;
  if (i < S3) {
    int l = i >> 10, row = i & 1023;
    const float* srcp = (row < 256) ? bq : (row < 512) ? bk : (row < 768) ? bv : bs;
    bqkvs[i] = srcp[l * 256 + (row & 255)];
    return;
  }
  i -= S3;
  if (i < S4) {
    bnode[i] = (i < 256) ? bec1[i] : ((i >= 512 && i < 768) ? bpp1[i - 512] : 0.f);
  }
}

// ---------------- GEMM: C[M,N] = A[M,K](bf16) * W[N,K]^T + bias -> bf16 ----------------
// 64x128 tile, BK=32, 4 waves (2x2, wave tile 32x64, acc[2][4]=32 VGPR),
// double-buffered LDS (24 KB -> ~6 blocks/CU). Occupancy-first for the
// latency-bound short-K shape (R9 counters: MfmaUtil/VALU both ~10%, Occ low).
// MFMA operands swapped (W-frag first): lane owns C[row][4 consecutive cols].
__global__ __launch_bounds__(256) void k_gemm64(
    const bf16_t* __restrict__ A, const bf16_t* __restrict__ W,
    const float* __restrict__ bias, bf16_t* __restrict__ Cb,
    int M, int N, int K) {
  __shared__ bf16_t As[2][64 * 32];
  __shared__ bf16_t Bs[2][128 * 32];
  const int t = threadIdx.x;
  const int lane = t & 63, wave = t >> 6;
  const int wm = wave >> 1, wn = wave & 1;
  const int mi = lane & 15, ks = lane >> 4;
  const int bm = blockIdx.x * 64, bn = blockIdx.y * 128;
  const int srow = lane >> 2;        // 0..15
  const int scol = (lane & 3) * 8;   // element col within BK
  int ra0 = bm + wave * 16 + srow;   // A: 16 rows per wave
  ra0 = (ra0 < M) ? ra0 : (M - 1);
  const int rb0 = bn + wave * 32 + srow;  // W: 32 rows per wave
  const int rb1 = rb0 + 16;

  auto stage = [&](int buf, int k0) {
    gload_lds16(A + (size_t)ra0 * K + k0 + scol, &As[buf][(wave * 16) * 32]);
    gload_lds16(W + (size_t)rb0 * K + k0 + scol, &Bs[buf][(wave * 32) * 32]);
    gload_lds16(W + (size_t)rb1 * K + k0 + scol, &Bs[buf][(wave * 32 + 16) * 32]);
  };

  f32x4 acc[2][4];
#pragma unroll
  for (int i = 0; i < 2; i++)
#pragma unroll
    for (int j = 0; j < 4; j++) acc[i][j] = (f32x4){0.f, 0.f, 0.f, 0.f};

  stage(0, 0);
  __syncthreads();
  const int nk = K >> 5;
  int cur = 0;
  for (int kt = 0; kt < nk; ++kt) {
    if (kt + 1 < nk) stage(cur ^ 1, (kt + 1) << 5);
    bf16x8 af[2], bfr[4];
#pragma unroll
    for (int i = 0; i < 2; i++)
      af[i] = *(const bf16x8*)&As[cur][(wm * 32 + i * 16 + mi) * 32 + ks * 8];
#pragma unroll
    for (int j = 0; j < 4; j++)
      bfr[j] = *(const bf16x8*)&Bs[cur][(wn * 64 + j * 16 + mi) * 32 + ks * 8];
#pragma unroll
    for (int i = 0; i < 2; i++)
#pragma unroll
      for (int j = 0; j < 4; j++) acc[i][j] = MFMA16(bfr[j], af[i], acc[i][j]);
    __syncthreads();
    cur ^= 1;
  }
  // epilogue: lane owns C[gm][gn..gn+3] per frag -> vector stores
#pragma unroll
  for (int i = 0; i < 2; i++) {
    int gm = bm + wm * 32 + i * 16 + mi;
    if (gm >= M) continue;
    size_t rowb = (size_t)gm * N;
#pragma unroll
    for (int j = 0; j < 4; j++) {
      int gn = bn + wn * 64 + j * 16 + ks * 4;
      f32x4 v = acc[i][j] + *(const f32x4*)(bias + gn);
      bf16x4 vb;
      vb[0] = (bf16_t)v[0]; vb[1] = (bf16_t)v[1];
      vb[2] = (bf16_t)v[2]; vb[3] = (bf16_t)v[3];
      *(bf16x4*)(Cb + rowb + gn) = vb;
    }
  }
}

// ---------------- CSR build ----------------
__global__ __launch_bounds__(256) void k_count(const int* __restrict__ dstv,
                                               int* __restrict__ counts, int E) {
  int e = blockIdx.x * 256 + threadIdx.x;
  if (e < E) atomicAdd(&counts[dstv[e]], 1);
}

// parallel 3-phase scan
__global__ __launch_bounds__(256) void k_scan_a(const int* __restrict__ counts,
                                                int* __restrict__ pre,
                                                int* __restrict__ blk, int n) {
  const int t = threadIdx.x;
  const int gid = blockIdx.x * 256 + t;
  const int lane = t & 63, wv = t >> 6;
  int c = (gid < n) ? counts[gid] : 0;
  int v = c;
#pragma unroll
  for (int off = 1; off < 64; off <<= 1) {
    int u = __shfl_up(v, off);
    if (lane >= off) v += u;
  }
  __shared__ int wsum[4];
  if (lane == 63) wsum[wv] = v;
  __syncthreads();
  if (t == 0) {
    int s = 0;
#pragma unroll
    for (int i = 0; i < 4; i++) { int x = wsum[i]; wsum[i] = s; s += x; }
  }
  __syncthreads();
  int excl = v - c + wsum[wv];
  if (gid < n) pre[gid] = excl;
  if (t == 255) blk[blockIdx.x] = excl + c;
}

__global__ __launch_bounds__(256) void k_scan_b(int* __restrict__ blk, int nb) {
  const int t = threadIdx.x;
  const int lane = t & 63, wv = t >> 6;
  int c = (t < nb) ? blk[t] : 0;
  int v = c;
#pragma unroll
  for (int off = 1; off < 64; off <<= 1) {
    int u = __shfl_up(v, off);
    if (lane >= off) v += u;
  }
  __shared__ int wsum[4];
  if (lane == 63) wsum[wv] = v;
  __syncthreads();
  if (t == 0) {
    int s = 0;
#pragma unroll
    for (int i = 0; i < 4; i++) { int x = wsum[i]; wsum[i] = s; s += x; }
  }
  __syncthreads();
  if (t < nb) blk[t] = v - c + wsum[wv];
}

__global__ __launch_bounds__(256) void k_scan_c(const int* __restrict__ counts,
                                                const int* __restrict__ pre,
                                                const int* __restrict__ blk,
                                                int* __restrict__ row_ptr,
                                                int* __restrict__ cursor, int n) {
  const int gid = blockIdx.x * 256 + threadIdx.x;
  if (gid >= n) return;
  int excl = blk[blockIdx.x] + pre[gid];
  cursor[gid] = excl;
  row_ptr[gid + 1] = excl + counts[gid];
  if (gid == 0) row_ptr[0] = 0;
}

__global__ __launch_bounds__(256) void k_fill(const int* __restrict__ srcv,
                                              const int* __restrict__ dstv,
                                              int* __restrict__ cursor,
                                              int* __restrict__ csr_src,
                                              int* __restrict__ csr_dst,
                                              int* __restrict__ csr_eid, int E) {
  int e = blockIdx.x * 256 + threadIdx.x;
  if (e < E) {
    int d = dstv[e];
    int slot = atomicAdd(&cursor[d], 1);
    csr_src[slot] = srcv[e];
    csr_dst[slot] = d;
    csr_eid[slot] = e;
  }
}

// ---------------- fused attention + residual + LayerNorm (bf16 residual stream) ----------------
// One wave per dst node; FOUR edges in flight (independent online-softmax states,
// compile-time-indexed arrays, pairwise merge at end). Lane covers cols 4l..4l+3.
__global__ __launch_bounds__(256) void k_attn_ln(
    const bf16_t* __restrict__ qkvs, const int* __restrict__ row_ptr,
    const int* __restrict__ csr_src, bf16_t* __restrict__ hb,
    const float* __restrict__ g, const float* __restrict__ b, int Nn) {
  const int lane = threadIdx.x & 63, wave = threadIdx.x >> 6;
  const int n = blockIdx.x * 4 + wave;
  if (n >= Nn) return;
  const float SC = 0.17677669529663688f;  // 1/sqrt(32)
  bf16x4 qv = *(const bf16x4*)(qkvs + (size_t)n * 1024 + lane * 4);
  float q0 = (float)qv[0] * SC, q1 = (float)qv[1] * SC;
  float q2 = (float)qv[2] * SC, q3 = (float)qv[3] * SC;
  float m[4], ls[4], a0[4], a1[4], a2[4], a3[4];
#pragma unroll
  for (int j = 0; j < 4; j++) {
    m[j] = -INFINITY; ls[j] = 0.f; a0[j] = 0.f; a1[j] = 0.f; a2[j] = 0.f; a3[j] = 0.f;
  }
  const int beg = row_ptr[n], end = row_ptr[n + 1];
  int idx = beg;
  for (; idx + 4 <= end; idx += 4) {
    int s[4];
    bf16x4 kv[4], vv[4];
#pragma unroll
    for (int j = 0; j < 4; j++) s[j] = csr_src[idx + j];
#pragma unroll
    for (int j = 0; j < 4; j++) {
      const bf16_t* base = qkvs + (size_t)s[j] * 1024;
      kv[j] = *(const bf16x4*)(base + 256 + lane * 4);
      vv[j] = *(const bf16x4*)(base + 512 + lane * 4);
    }
    float d[4];
#pragma unroll
    for (int j = 0; j < 4; j++)
      d[j] = q0 * (float)kv[j][0] + q1 * (float)kv[j][1] +
             q2 * (float)kv[j][2] + q3 * (float)kv[j][3];
#pragma unroll
    for (int j = 0; j < 4; j++) d[j] += __shfl_xor(d[j], 1);
#pragma unroll
    for (int j = 0; j < 4; j++) d[j] += __shfl_xor(d[j], 2);
#pragma unroll
    for (int j = 0; j < 4; j++) d[j] += __shfl_xor(d[j], 4);
#pragma unroll
    for (int j = 0; j < 4; j++) {
      float mn = fmaxf(m[j], d[j]);
      float sc = __expf(m[j] - mn);
      float p = __expf(d[j] - mn);
      ls[j] = ls[j] * sc + p;
      a0[j] = a0[j] * sc + p * (float)vv[j][0];
      a1[j] = a1[j] * sc + p * (float)vv[j][1];
      a2[j] = a2[j] * sc + p * (float)vv[j][2];
      a3[j] = a3[j] * sc + p * (float)vv[j][3];
      m[j] = mn;
    }
  }
  for (; idx < end; ++idx) {
    int s0 = csr_src[idx];
    const bf16_t* base = qkvs + (size_t)s0 * 1024;
    bf16x4 kv = *(const bf16x4*)(base + 256 + lane * 4);
    bf16x4 vv = *(const bf16x4*)(base + 512 + lane * 4);
    float d = q0 * (float)kv[0] + q1 * (float)kv[1] + q2 * (float)kv[2] + q3 * (float)kv[3];
    d += __shfl_xor(d, 1);
    d += __shfl_xor(d, 2);
    d += __shfl_xor(d, 4);
    float mn = fmaxf(m[0], d);
    float sc = __expf(m[0] - mn);
    float p = __expf(d - mn);
    ls[0] = ls[0] * sc + p;
    a0[0] = a0[0] * sc + p * (float)vv[0];
    a1[0] = a1[0] * sc + p * (float)vv[1];
    a2[0] = a2[0] * sc + p * (float)vv[2];
    a3[0] = a3[0] * sc + p * (float)vv[3];
    m[0] = mn;
  }
  // pairwise merge 0<-2, 1<-3, 0<-1 (guard: -inf states -> scale 1, sums 0)
#pragma unroll
  for (int step = 0; step < 3; ++step) {
    int dst = (step == 2) ? 0 : step;
    int src = (step == 2) ? 1 : step + 2;
    float mn = fmaxf(m[dst], m[src]);
    float sD = (m[dst] == mn) ? 1.f : __expf(m[dst] - mn);
    float sS = (m[src] == mn) ? 1.f : __expf(m[src] - mn);
    ls[dst] = ls[dst] * sD + ls[src] * sS;
    a0[dst] = a0[dst] * sD + a0[src] * sS;
    a1[dst] = a1[dst] * sD + a1[src] * sS;
    a2[dst] = a2[dst] * sD + a2[src] * sS;
    a3[dst] = a3[dst] * sD + a3[src] * sS;
    m[dst] = mn;
  }
  float inv = 1.f / (ls[0] + 1e-16f);
  // residual (bf16) + skip + LN (wave owns the full 256-dim row)
  const int c = lane * 4;
  bf16x4 hv = *(const bf16x4*)(hb + (size_t)n * 256 + c);
  bf16x4 sv = *(const bf16x4*)(qkvs + (size_t)n * 1024 + 768 + c);
  float x0 = (float)hv[0] + a0[0] * inv + (float)sv[0];
  float x1 = (float)hv[1] + a1[0] * inv + (float)sv[1];
  float x2 = (float)hv[2] + a2[0] * inv + (float)sv[2];
  float x3 = (float)hv[3] + a3[0] * inv + (float)sv[3];
  float sum = x0 + x1 + x2 + x3;
  float sq = x0 * x0 + x1 * x1 + x2 * x2 + x3 * x3;
#pragma unroll
  for (int mm = 1; mm < 64; mm <<= 1) {
    sum += __shfl_xor(sum, mm);
    sq += __shfl_xor(sq, mm);
  }
  float mu = sum * (1.f / 256.f);
  float var = sq * (1.f / 256.f) - mu * mu;
  float rs = rsqrtf(var + 1e-5f);
  f32x4 y;
  y[0] = (x0 - mu) * rs * g[c] + b[c];
  y[1] = (x1 - mu) * rs * g[c + 1] + b[c + 1];
  y[2] = (x2 - mu) * rs * g[c + 2] + b[c + 2];
  y[3] = (x3 - mu) * rs * g[c + 3] + b[c + 3];
  bf16x4 yb;
  yb[0] = (bf16_t)y[0]; yb[1] = (bf16_t)y[1]; yb[2] = (bf16_t)y[2]; yb[3] = (bf16_t)y[3];
  *(bf16x4*)(hb + (size_t)n * 256 + c) = yb;
}

// ---------------- edge head final over dst-sorted CSR ----------------
// 16 lanes per group; each group owns 8 consecutive CSR slots (dst-side tables
// cached across same-dst runs). Vectorized f32x4 math (packed add/fma).
#define EF_SLOTS 8
__device__ __forceinline__ f32x4 cvt_lo(bf16x8 v) {
  bf16x4 h = __builtin_shufflevector(v, v, 0, 1, 2, 3);
  return __builtin_convertvector(h, f32x4);
}
__device__ __forceinline__ f32x4 cvt_hi(bf16x8 v) {
  bf16x4 h = __builtin_shufflevector(v, v, 4, 5, 6, 7);
  return __builtin_convertvector(h, f32x4);
}
__global__ __launch_bounds__(256) void k_edge_final(
    const bf16_t* __restrict__ Pb, const int* __restrict__ csr_src,
    const int* __restrict__ csr_dst, const int* __restrict__ csr_eid,
    const float* __restrict__ wec2, const float* __restrict__ wpp2,
    const float* __restrict__ bec2, const float* __restrict__ bpp2,
    float* __restrict__ out, int E) {
  const int t = threadIdx.x;
  const int sub = t & 15;
  const int grp = blockIdx.x * 16 + (t >> 4);
  const int slot0 = grp * EF_SLOTS;
  if (slot0 >= E) return;
  const int slot1 = (slot0 + EF_SLOTS < E) ? slot0 + EF_SLOTS : E;
  f32x4 w_ec[2][2], w_p0[2][2], w_p1[2][2];
#pragma unroll
  for (int h = 0; h < 2; h++) {
    int cb = h * 128 + sub * 8;
    w_ec[h][0] = *(const f32x4*)(wec2 + cb);
    w_ec[h][1] = *(const f32x4*)(wec2 + cb + 4);
    w_p0[h][0] = *(const f32x4*)(wpp2 + cb);
    w_p0[h][1] = *(const f32x4*)(wpp2 + cb + 4);
    w_p1[h][0] = *(const f32x4*)(wpp2 + 256 + cb);
    w_p1[h][1] = *(const f32x4*)(wpp2 + 256 + cb + 4);
  }
  const float be = bec2[0], bp0 = bpp2[0], bp1 = bpp2[1];
  const f32x4 zero = (f32x4){0.f, 0.f, 0.f, 0.f};
  int cur_dst = -1;
  f32x4 eR[2][2], pR[2][2];
  for (int slot = slot0; slot < slot1; ++slot) {
    int dn = csr_dst[slot];
    if (dn != cur_dst) {  // group-uniform branch (slots share dst in runs)
      cur_dst = dn;
      const bf16_t* pd = Pb + (size_t)dn * 1024;
#pragma unroll
      for (int h = 0; h < 2; h++) {
        int cb = h * 128 + sub * 8;
        bf16x8 a = *(const bf16x8*)(pd + 256 + cb);
        bf16x8 p = *(const bf16x8*)(pd + 768 + cb);
        eR[h][0] = cvt_lo(a);
        eR[h][1] = cvt_hi(a);
        pR[h][0] = cvt_lo(p);
        pR[h][1] = cvt_hi(p);
      }
    }
    const bf16_t* ps = Pb + (size_t)csr_src[slot] * 1024;
    f32x4 v0 = zero, v1 = zero, v2 = zero;
#pragma unroll
    for (int h = 0; h < 2; h++) {
      int cb = h * 128 + sub * 8;
      bf16x8 eL = *(const bf16x8*)(ps + cb);
      bf16x8 pL = *(const bf16x8*)(ps + 512 + cb);
      f32x4 el0 = cvt_lo(eL), el1 = cvt_hi(eL);
      f32x4 pl0 = cvt_lo(pL), pl1 = cvt_hi(pL);
      f32x4 he0 = __builtin_elementwise_max(el0 + eR[h][0], zero);
      f32x4 he1 = __builtin_elementwise_max(el1 + eR[h][1], zero);
      f32x4 hp0 = __builtin_elementwise_max(pl0 + pR[h][0], zero);
      f32x4 hp1 = __builtin_elementwise_max(pl1 + pR[h][1], zero);
      v0 += he0 * w_ec[h][0] + he1 * w_ec[h][1];
      v1 += hp0 * w_p0[h][0] + hp1 * w_p0[h][1];
      v2 += hp0 * w_p1[h][0] + hp1 * w_p1[h][1];
    }
    float s0 = v0[0] + v0[1] + v0[2] + v0[3];
    float s1 = v1[0] + v1[1] + v1[2] + v1[3];
    float s2 = v2[0] + v2[1] + v2[2] + v2[3];
#pragma unroll
    for (int mm = 1; mm < 16; mm <<= 1) {
      s0 += __shfl_xor(s0, mm);
      s1 += __shfl_xor(s1, mm);
      s2 += __shfl_xor(s2, mm);
    }
    if (sub == 0) {
      int eid = csr_eid[slot];
      out[eid] = s0 + be;
      float p0 = s1 + bp0;
      float p1 = s2 + bp1;
      // stable softplus = max(x,0) + log1p(exp(-|x|))
      out[(size_t)E + 2 * eid]     = fmaxf(p0, 0.f) + log1pf(__expf(-fabsf(p0)));
      out[(size_t)E + 2 * eid + 1] = fmaxf(p1, 0.f) + log1pf(__expf(-fabsf(p1)));
    }
  }
}

extern "C" void kernel_launch(void* const* d_in, const int* in_sizes, int n_in,
                              void* d_out, int out_size, void* d_ws, size_t ws_size,
                              hipStream_t stream) {
  const float* x    = (const float*)d_in[0];
  const int*   ei   = (const int*)d_in[1];
  const float* W_in = (const float*)d_in[2];
  const float* b_in = (const float*)d_in[3];
  const float* Wq   = (const float*)d_in[4];
  const float* bq   = (const float*)d_in[5];
  const float* Wk   = (const float*)d_in[6];
  const float* bk   = (const float*)d_in[7];
  const float* Wv   = (const float*)d_in[8];
  const float* bv   = (const float*)d_in[9];
  const float* Ws   = (const float*)d_in[10];
  const float* bs   = (const float*)d_in[11];
  const float* ln_g = (const float*)d_in[12];
  const float* ln_b = (const float*)d_in[13];
  const float* Wec1 = (const float*)d_in[14];
  const float* bec1 = (const float*)d_in[15];
  const float* Wec2 = (const float*)d_in[16];
  const float* bec2 = (const float*)d_in[17];
  const float* Wpp1 = (const float*)d_in[18];
  const float* bpp1 = (const float*)d_in[19];
  const float* Wpp2 = (const float*)d_in[20];
  const float* bpp2 = (const float*)d_in[21];

  const int N = in_sizes[0] / 128;
  const int E = in_sizes[1] / 2;
  const int* srcv = ei;
  const int* dstv = ei + E;
  const int NB = (N + 255) / 256;

  // ---- carve workspace ----
  char* w = (char*)d_ws;
  size_t off = 0;
  auto carve = [&](size_t bytes) -> char* {
    char* p = w + off;
    off = (off + bytes + 255) & ~(size_t)255;
    return p;
  };
  bf16_t* xb      = (bf16_t*)carve((size_t)N * 128 * 2);
  bf16_t* hb      = (bf16_t*)carve((size_t)N * 256 * 2);
  bf16_t* qkvsb   = (bf16_t*)carve((size_t)N * 1024 * 2);  // reused as Pb after layers
  bf16_t* w_in_b  = (bf16_t*)carve((size_t)256 * 128 * 2);
  bf16_t* wqkvs_b = (bf16_t*)carve((size_t)3 * 1024 * 256 * 2);
  float*  bqkvs   = (float*) carve((size_t)3 * 1024 * 4);
  bf16_t* wnode_b = (bf16_t*)carve((size_t)1024 * 256 * 2);
  float*  bnode   = (float*) carve((size_t)1024 * 4);
  int*    counts  = (int*)   carve((size_t)N * 4);
  int*    row_ptr = (int*)   carve((size_t)(N + 1) * 4);
  int*    cursor  = (int*)   carve((size_t)N * 4);
  int*    pre     = (int*)   carve((size_t)N * 4);
  int*    blk     = (int*)   carve((size_t)256 * 4);
  int*    csr_src = (int*)   carve((size_t)E * 4);
  int*    csr_dst = (int*)   carve((size_t)E * 4);
  int*    csr_eid = (int*)   carve((size_t)E * 4);

  hipMemsetAsync(counts, 0, (size_t)N * 4, stream);

  // ---- prep ----
  int n4 = N * 128 / 4;
  k_cvt4<<<dim3((n4 + 255) / 256), dim3(256), 0, stream>>>(x, xb, n4);
  const int PREP_TOT = 256 * 128 + 3 * 1024 * 256 + 1024 * 256 + 3 * 1024 + 1024;
  k_prep_w<<<dim3((PREP_TOT + 255) / 256), dim3(256), 0, stream>>>(
      W_in, Wq, Wk, Wv, Ws, bq, bk, bv, bs, Wec1, Wpp1, bec1, bpp1,
      w_in_b, wqkvs_b, bqkvs, wnode_b, bnode);

  // ---- input projection: h0 = x @ W_in^T + b_in (bf16 residual stream) ----
  k_gemm64<<<dim3((N + 63) / 64, 2), dim3(256), 0, stream>>>(
      xb, w_in_b, b_in, hb, N, 256, 128);

  // ---- CSR build (parallel 3-phase scan) ----
  k_count<<<dim3((E + 255) / 256), dim3(256), 0, stream>>>(dstv, counts, E);
  k_scan_a<<<dim3(NB), dim3(256), 0, stream>>>(counts, pre, blk, N);
  k_scan_b<<<dim3(1), dim3(256), 0, stream>>>(blk, NB);
  k_scan_c<<<dim3(NB), dim3(256), 0, stream>>>(counts, pre, blk, row_ptr, cursor, N);
  k_fill<<<dim3((E + 255) / 256), dim3(256), 0, stream>>>(
      srcv, dstv, cursor, csr_src, csr_dst, csr_eid, E);

  // ---- 3 transformer layers ----
  for (int l = 0; l < 3; ++l) {
    k_gemm64<<<dim3((N + 63) / 64, 8), dim3(256), 0, stream>>>(
        hb, wqkvs_b + (size_t)l * 1024 * 256, bqkvs + l * 1024, qkvsb, N, 1024, 256);
    k_attn_ln<<<dim3((N + 3) / 4), dim3(256), 0, stream>>>(
        qkvsb, row_ptr, csr_src, hb, ln_g + l * 256, ln_b + l * 256, N);
  }

  // ---- edge heads: per-node P tables (into qkvsb, now free), then per-edge finish ----
  k_gemm64<<<dim3((N + 63) / 64, 8), dim3(256), 0, stream>>>(
      hb, wnode_b, bnode, qkvsb, N, 1024, 256);
  int ngroups = (E + EF_SLOTS - 1) / EF_SLOTS;
  k_edge_final<<<dim3((ngroups + 15) / 16), dim3(256), 0, stream>>>(
      qkvsb, csr_src, csr_dst, csr_eid, Wec2, Wpp2, bec2, bpp2, (float*)d_out, E);
}

// Round 12
// 772.268 us; speedup vs baseline: 1.0123x; 1.0123x over previous
//
#include <hip/hip_runtime.h>
#include <math.h>

typedef __bf16 bf16_t;
typedef __attribute__((ext_vector_type(8))) __bf16 bf16x8;
typedef __attribute__((ext_vector_type(4))) __bf16 bf16x4;
typedef __attribute__((ext_vector_type(4))) float f32x4;

#define MFMA16(a,b,c) __builtin_amdgcn_mfma_f32_16x16x32_bf16((a),(b),(c),0,0,0)

// async global->LDS, 16B per lane, LDS dest = base + lane*16 (wave-uniform base)
__device__ __forceinline__ void gload_lds16(const bf16_t* g, bf16_t* l) {
  __builtin_amdgcn_global_load_lds(
      (const __attribute__((address_space(1))) unsigned int*)g,
      (__attribute__((address_space(3))) unsigned int*)l, 16, 0, 0);
}

// ---------------- prep: fp32 -> bf16 conversions ----------------
__global__ __launch_bounds__(256) void k_cvt4(const float* __restrict__ x,
                                              bf16_t* __restrict__ o, int n4) {
  int i = blockIdx.x * 256 + threadIdx.x;
  if (i >= n4) return;
  f32x4 v = *(const f32x4*)(x + (size_t)i * 4);
  bf16x4 b;
  b[0] = (bf16_t)v[0]; b[1] = (bf16_t)v[1]; b[2] = (bf16_t)v[2]; b[3] = (bf16_t)v[3];
  *(bf16x4*)(o + (size_t)i * 4) = b;
}

// builds: w_in_b[256*128], wqkvs_b[3][1024][256] (q|k|v|s rows), bqkvs[3][1024],
//         wnode_b[1024][256] = [Wec1_L | Wec1_R | Wpp1_L | Wpp1_R] rows,
//         bnode[1024] = [bec1 | 0 | bpp1 | 0]
__global__ __launch_bounds__(256) void k_prep_w(
    const float* __restrict__ W_in,
    const float* __restrict__ Wq, const float* __restrict__ Wk,
    const float* __restrict__ Wv, const float* __restrict__ Ws,
    const float* __restrict__ bq, const float* __restrict__ bk,
    const float* __restrict__ bv, const float* __restrict__ bs,
    const float* __restrict__ Wec1, const float* __restrict__ Wpp1,
    const float* __restrict__ bec1, const float* __restrict__ bpp1,
    bf16_t* __restrict__ w_in_b, bf16_t* __restrict__ wqkvs_b,
    float* __restrict__ bqkvs, bf16_t* __restrict__ wnode_b,
    float* __restrict__ bnode) {
  int i = blockIdx.x * 256 + threadIdx.x;
  const int S0 = 256 * 128, S1 = 3 * 1024 * 256, S2 = 1024 * 256, S3 = 3 * 1024, S4 = 1024;
  if (i < S0) { w_in_b[i] = (bf16_t)W_in[i]; return; }
  i -= S0;
  if (i < S1) {
    int l = i / (1024 * 256), rem = i % (1024 * 256);
    int row = rem >> 8, col = rem & 255;
    const float* srcp = (row < 256) ? Wq : (row < 512) ? Wk : (row < 768) ? Wv : Ws;
    wqkvs_b[i] = (bf16_t)srcp[((size_t)l * 256 + (row & 255)) * 256 + col];
    return;
  }
  i -= S1;
  if (i < S2) {
    int row = i >> 8, col = i & 255;
    float v;
    if (row < 256)       v = Wec1[row * 512 + col];
    else if (row < 512)  v = Wec1[(row - 256) * 512 + 256 + col];
    else if (row < 768)  v = Wpp1[(row - 512) * 512 + col];
    else                 v = Wpp1[(row - 768) * 512 + 256 + col];
    wnode_b[i] = (bf16_t)v;
    return;
  }
  i -= S2;
  if (i < S3) {
    int l = i >> 10, row = i & 1023;
    const float* srcp = (row < 256) ? bq : (row < 512) ? bk : (row < 768) ? bv : bs;
    bqkvs[i] = srcp[l * 256 + (row & 255)];
    return;
  }
  i -= S3;
  if (i < S4) {
    bnode[i] = (i < 256) ? bec1[i] : ((i >= 512 && i < 768) ? bpp1[i - 512] : 0.f);
  }
}

// ---------------- GEMM: C[M,N] = A[M,K](bf16) * W[N,K]^T + bias -> bf16 ----------------
// 128x128 tile, BK=32, 4 waves, double-buffered LDS (32 KB) — proven R10 structure.
// GRID TRANSPOSED: blockIdx.x = col-block (few), blockIdx.y = row-block (many),
// so consecutively-dispatched blocks share the same A-tile (L2/L3-hot reuse).
// MFMA operands swapped (W-frag first): lane owns C[row][4 consecutive cols].
__global__ __launch_bounds__(256) void k_gemm128(
    const bf16_t* __restrict__ A, const bf16_t* __restrict__ W,
    const float* __restrict__ bias, bf16_t* __restrict__ Cb,
    int M, int N, int K) {
  __shared__ bf16_t As[2][128 * 32];
  __shared__ bf16_t Bs[2][128 * 32];
  const int t = threadIdx.x;
  const int lane = t & 63, wave = t >> 6;
  const int wm = wave >> 1, wn = wave & 1;
  const int mi = lane & 15, ks = lane >> 4;
  const int bm = blockIdx.y * 128, bn = blockIdx.x * 128;
  const int scol = (lane & 3) * 8;   // element col within BK
  int ra0 = bm + wave * 32 + (lane >> 2);
  int ra1 = ra0 + 16;
  ra0 = (ra0 < M) ? ra0 : (M - 1);
  ra1 = (ra1 < M) ? ra1 : (M - 1);
  const int rb0 = bn + wave * 32 + (lane >> 2);
  const int rb1 = rb0 + 16;

  auto stage = [&](int buf, int k0) {
    gload_lds16(A + (size_t)ra0 * K + k0 + scol, &As[buf][(wave * 32) * 32]);
    gload_lds16(A + (size_t)ra1 * K + k0 + scol, &As[buf][(wave * 32 + 16) * 32]);
    gload_lds16(W + (size_t)rb0 * K + k0 + scol, &Bs[buf][(wave * 32) * 32]);
    gload_lds16(W + (size_t)rb1 * K + k0 + scol, &Bs[buf][(wave * 32 + 16) * 32]);
  };

  f32x4 acc[4][4];
#pragma unroll
  for (int i = 0; i < 4; i++)
#pragma unroll
    for (int j = 0; j < 4; j++) acc[i][j] = (f32x4){0.f, 0.f, 0.f, 0.f};

  stage(0, 0);
  __syncthreads();
  const int nk = K >> 5;
  int cur = 0;
  for (int kt = 0; kt < nk; ++kt) {
    if (kt + 1 < nk) stage(cur ^ 1, (kt + 1) << 5);
    bf16x8 af[4], bfr[4];
#pragma unroll
    for (int i = 0; i < 4; i++)
      af[i] = *(const bf16x8*)&As[cur][(wm * 64 + i * 16 + mi) * 32 + ks * 8];
#pragma unroll
    for (int j = 0; j < 4; j++)
      bfr[j] = *(const bf16x8*)&Bs[cur][(wn * 64 + j * 16 + mi) * 32 + ks * 8];
#pragma unroll
    for (int i = 0; i < 4; i++)
#pragma unroll
      for (int j = 0; j < 4; j++) acc[i][j] = MFMA16(bfr[j], af[i], acc[i][j]);
    __syncthreads();
    cur ^= 1;
  }
  // epilogue: lane owns C[gm][gn..gn+3] per frag -> vector stores
#pragma unroll
  for (int i = 0; i < 4; i++) {
    int gm = bm + wm * 64 + i * 16 + mi;
    if (gm >= M) continue;
    size_t rowb = (size_t)gm * N;
#pragma unroll
    for (int j = 0; j < 4; j++) {
      int gn = bn + wn * 64 + j * 16 + ks * 4;
      f32x4 v = acc[i][j] + *(const f32x4*)(bias + gn);
      bf16x4 vb;
      vb[0] = (bf16_t)v[0]; vb[1] = (bf16_t)v[1];
      vb[2] = (bf16_t)v[2]; vb[3] = (bf16_t)v[3];
      *(bf16x4*)(Cb + rowb + gn) = vb;
    }
  }
}

// ---------------- CSR build ----------------
__global__ __launch_bounds__(256) void k_count(const int* __restrict__ dstv,
                                               int* __restrict__ counts, int E) {
  int e = blockIdx.x * 256 + threadIdx.x;
  if (e < E) atomicAdd(&counts[dstv[e]], 1);
}

// parallel 3-phase scan
__global__ __launch_bounds__(256) void k_scan_a(const int* __restrict__ counts,
                                                int* __restrict__ pre,
                                                int* __restrict__ blk, int n) {
  const int t = threadIdx.x;
  const int gid = blockIdx.x * 256 + t;
  const int lane = t & 63, wv = t >> 6;
  int c = (gid < n) ? counts[gid] : 0;
  int v = c;
#pragma unroll
  for (int off = 1; off < 64; off <<= 1) {
    int u = __shfl_up(v, off);
    if (lane >= off) v += u;
  }
  __shared__ int wsum[4];
  if (lane == 63) wsum[wv] = v;
  __syncthreads();
  if (t == 0) {
    int s = 0;
#pragma unroll
    for (int i = 0; i < 4; i++) { int x = wsum[i]; wsum[i] = s; s += x; }
  }
  __syncthreads();
  int excl = v - c + wsum[wv];
  if (gid < n) pre[gid] = excl;
  if (t == 255) blk[blockIdx.x] = excl + c;
}

__global__ __launch_bounds__(256) void k_scan_b(int* __restrict__ blk, int nb) {
  const int t = threadIdx.x;
  const int lane = t & 63, wv = t >> 6;
  int c = (t < nb) ? blk[t] : 0;
  int v = c;
#pragma unroll
  for (int off = 1; off < 64; off <<= 1) {
    int u = __shfl_up(v, off);
    if (lane >= off) v += u;
  }
  __shared__ int wsum[4];
  if (lane == 63) wsum[wv] = v;
  __syncthreads();
  if (t == 0) {
    int s = 0;
#pragma unroll
    for (int i = 0; i < 4; i++) { int x = wsum[i]; wsum[i] = s; s += x; }
  }
  __syncthreads();
  if (t < nb) blk[t] = v - c + wsum[wv];
}

__global__ __launch_bounds__(256) void k_scan_c(const int* __restrict__ counts,
                                                const int* __restrict__ pre,
                                                const int* __restrict__ blk,
                                                int* __restrict__ row_ptr,
                                                int* __restrict__ cursor, int n) {
  const int gid = blockIdx.x * 256 + threadIdx.x;
  if (gid >= n) return;
  int excl = blk[blockIdx.x] + pre[gid];
  cursor[gid] = excl;
  row_ptr[gid + 1] = excl + counts[gid];
  if (gid == 0) row_ptr[0] = 0;
}

__global__ __launch_bounds__(256) void k_fill(const int* __restrict__ srcv,
                                              const int* __restrict__ dstv,
                                              int* __restrict__ cursor,
                                              int* __restrict__ csr_src,
                                              int* __restrict__ csr_dst,
                                              int* __restrict__ csr_eid, int E) {
  int e = blockIdx.x * 256 + threadIdx.x;
  if (e < E) {
    int d = dstv[e];
    int slot = atomicAdd(&cursor[d], 1);
    csr_src[slot] = srcv[e];
    csr_dst[slot] = d;
    csr_eid[slot] = e;
  }
}

// ---------------- fused attention + residual + LayerNorm (bf16 residual stream) ----------------
// One wave per dst node; FOUR edges in flight (independent online-softmax states,
// compile-time-indexed arrays, pairwise merge at end). Lane covers cols 4l..4l+3.
__global__ __launch_bounds__(256) void k_attn_ln(
    const bf16_t* __restrict__ qkvs, const int* __restrict__ row_ptr,
    const int* __restrict__ csr_src, bf16_t* __restrict__ hb,
    const float* __restrict__ g, const float* __restrict__ b, int Nn) {
  const int lane = threadIdx.x & 63, wave = threadIdx.x >> 6;
  const int n = blockIdx.x * 4 + wave;
  if (n >= Nn) return;
  const float SC = 0.17677669529663688f;  // 1/sqrt(32)
  bf16x4 qv = *(const bf16x4*)(qkvs + (size_t)n * 1024 + lane * 4);
  float q0 = (float)qv[0] * SC, q1 = (float)qv[1] * SC;
  float q2 = (float)qv[2] * SC, q3 = (float)qv[3] * SC;
  float m[4], ls[4], a0[4], a1[4], a2[4], a3[4];
#pragma unroll
  for (int j = 0; j < 4; j++) {
    m[j] = -INFINITY; ls[j] = 0.f; a0[j] = 0.f; a1[j] = 0.f; a2[j] = 0.f; a3[j] = 0.f;
  }
  const int beg = row_ptr[n], end = row_ptr[n + 1];
  int idx = beg;
  for (; idx + 4 <= end; idx += 4) {
    int s[4];
    bf16x4 kv[4], vv[4];
#pragma unroll
    for (int j = 0; j < 4; j++) s[j] = csr_src[idx + j];
#pragma unroll
    for (int j = 0; j < 4; j++) {
      const bf16_t* base = qkvs + (size_t)s[j] * 1024;
      kv[j] = *(const bf16x4*)(base + 256 + lane * 4);
      vv[j] = *(const bf16x4*)(base + 512 + lane * 4);
    }
    float d[4];
#pragma unroll
    for (int j = 0; j < 4; j++)
      d[j] = q0 * (float)kv[j][0] + q1 * (float)kv[j][1] +
             q2 * (float)kv[j][2] + q3 * (float)kv[j][3];
#pragma unroll
    for (int j = 0; j < 4; j++) d[j] += __shfl_xor(d[j], 1);
#pragma unroll
    for (int j = 0; j < 4; j++) d[j] += __shfl_xor(d[j], 2);
#pragma unroll
    for (int j = 0; j < 4; j++) d[j] += __shfl_xor(d[j], 4);
#pragma unroll
    for (int j = 0; j < 4; j++) {
      float mn = fmaxf(m[j], d[j]);
      float sc = __expf(m[j] - mn);
      float p = __expf(d[j] - mn);
      ls[j] = ls[j] * sc + p;
      a0[j] = a0[j] * sc + p * (float)vv[j][0];
      a1[j] = a1[j] * sc + p * (float)vv[j][1];
      a2[j] = a2[j] * sc + p * (float)vv[j][2];
      a3[j] = a3[j] * sc + p * (float)vv[j][3];
      m[j] = mn;
    }
  }
  for (; idx < end; ++idx) {
    int s0 = csr_src[idx];
    const bf16_t* base = qkvs + (size_t)s0 * 1024;
    bf16x4 kv = *(const bf16x4*)(base + 256 + lane * 4);
    bf16x4 vv = *(const bf16x4*)(base + 512 + lane * 4);
    float d = q0 * (float)kv[0] + q1 * (float)kv[1] + q2 * (float)kv[2] + q3 * (float)kv[3];
    d += __shfl_xor(d, 1);
    d += __shfl_xor(d, 2);
    d += __shfl_xor(d, 4);
    float mn = fmaxf(m[0], d);
    float sc = __expf(m[0] - mn);
    float p = __expf(d - mn);
    ls[0] = ls[0] * sc + p;
    a0[0] = a0[0] * sc + p * (float)vv[0];
    a1[0] = a1[0] * sc + p * (float)vv[1];
    a2[0] = a2[0] * sc + p * (float)vv[2];
    a3[0] = a3[0] * sc + p * (float)vv[3];
    m[0] = mn;
  }
  // pairwise merge 0<-2, 1<-3, 0<-1 (guard: -inf states -> scale 1, sums 0)
#pragma unroll
  for (int step = 0; step < 3; ++step) {
    int dst = (step == 2) ? 0 : step;
    int src = (step == 2) ? 1 : step + 2;
    float mn = fmaxf(m[dst], m[src]);
    float sD = (m[dst] == mn) ? 1.f : __expf(m[dst] - mn);
    float sS = (m[src] == mn) ? 1.f : __expf(m[src] - mn);
    ls[dst] = ls[dst] * sD + ls[src] * sS;
    a0[dst] = a0[dst] * sD + a0[src] * sS;
    a1[dst] = a1[dst] * sD + a1[src] * sS;
    a2[dst] = a2[dst] * sD + a2[src] * sS;
    a3[dst] = a3[dst] * sD + a3[src] * sS;
    m[dst] = mn;
  }
  float inv = 1.f / (ls[0] + 1e-16f);
  // residual (bf16) + skip + LN (wave owns the full 256-dim row)
  const int c = lane * 4;
  bf16x4 hv = *(const bf16x4*)(hb + (size_t)n * 256 + c);
  bf16x4 sv = *(const bf16x4*)(qkvs + (size_t)n * 1024 + 768 + c);
  float x0 = (float)hv[0] + a0[0] * inv + (float)sv[0];
  float x1 = (float)hv[1] + a1[0] * inv + (float)sv[1];
  float x2 = (float)hv[2] + a2[0] * inv + (float)sv[2];
  float x3 = (float)hv[3] + a3[0] * inv + (float)sv[3];
  float sum = x0 + x1 + x2 + x3;
  float sq = x0 * x0 + x1 * x1 + x2 * x2 + x3 * x3;
#pragma unroll
  for (int mm = 1; mm < 64; mm <<= 1) {
    sum += __shfl_xor(sum, mm);
    sq += __shfl_xor(sq, mm);
  }
  float mu = sum * (1.f / 256.f);
  float var = sq * (1.f / 256.f) - mu * mu;
  float rs = rsqrtf(var + 1e-5f);
  f32x4 y;
  y[0] = (x0 - mu) * rs * g[c] + b[c];
  y[1] = (x1 - mu) * rs * g[c + 1] + b[c + 1];
  y[2] = (x2 - mu) * rs * g[c + 2] + b[c + 2];
  y[3] = (x3 - mu) * rs * g[c + 3] + b[c + 3];
  bf16x4 yb;
  yb[0] = (bf16_t)y[0]; yb[1] = (bf16_t)y[1]; yb[2] = (bf16_t)y[2]; yb[3] = (bf16_t)y[3];
  *(bf16x4*)(hb + (size_t)n * 256 + c) = yb;
}

// ---------------- edge head final over dst-sorted CSR ----------------
// 16 lanes per group; each group owns 8 consecutive CSR slots (dst-side tables
// cached across same-dst runs). 2-stage software pipeline: slot+1's src-row
// loads are issued before slot's compute, hiding gather latency under VALU.
#define EF_SLOTS 8
__device__ __forceinline__ f32x4 cvt_lo(bf16x8 v) {
  bf16x4 h = __builtin_shufflevector(v, v, 0, 1, 2, 3);
  return __builtin_convertvector(h, f32x4);
}
__device__ __forceinline__ f32x4 cvt_hi(bf16x8 v) {
  bf16x4 h = __builtin_shufflevector(v, v, 4, 5, 6, 7);
  return __builtin_convertvector(h, f32x4);
}
__global__ __launch_bounds__(256) void k_edge_final(
    const bf16_t* __restrict__ Pb, const int* __restrict__ csr_src,
    const int* __restrict__ csr_dst, const int* __restrict__ csr_eid,
    const float* __restrict__ wec2, const float* __restrict__ wpp2,
    const float* __restrict__ bec2, const float* __restrict__ bpp2,
    float* __restrict__ out, int E) {
  const int t = threadIdx.x;
  const int sub = t & 15;
  const int grp = blockIdx.x * 16 + (t >> 4);
  const int slot0 = grp * EF_SLOTS;
  if (slot0 >= E) return;
  const int slot1 = (slot0 + EF_SLOTS < E) ? slot0 + EF_SLOTS : E;
  f32x4 w_ec[2][2], w_p0[2][2], w_p1[2][2];
#pragma unroll
  for (int h = 0; h < 2; h++) {
    int cb = h * 128 + sub * 8;
    w_ec[h][0] = *(const f32x4*)(wec2 + cb);
    w_ec[h][1] = *(const f32x4*)(wec2 + cb + 4);
    w_p0[h][0] = *(const f32x4*)(wpp2 + cb);
    w_p0[h][1] = *(const f32x4*)(wpp2 + cb + 4);
    w_p1[h][0] = *(const f32x4*)(wpp2 + 256 + cb);
    w_p1[h][1] = *(const f32x4*)(wpp2 + 256 + cb + 4);
  }
  const float be = bec2[0], bp0 = bpp2[0], bp1 = bpp2[1];
  const f32x4 zero = (f32x4){0.f, 0.f, 0.f, 0.f};
  int cur_dst = -1;
  f32x4 eR[2][2], pR[2][2];
  // prologue: load slot0's src rows
  bf16x8 eLc[2], pLc[2];
  {
    const bf16_t* ps = Pb + (size_t)csr_src[slot0] * 1024;
#pragma unroll
    for (int h = 0; h < 2; h++) {
      int cb = h * 128 + sub * 8;
      eLc[h] = *(const bf16x8*)(ps + cb);
      pLc[h] = *(const bf16x8*)(ps + 512 + cb);
    }
  }
  for (int slot = slot0; slot < slot1; ++slot) {
    // prefetch next slot's src rows (issued before compute; latency hidden)
    bf16x8 eLn[2] = {eLc[0], eLc[1]}, pLn[2] = {pLc[0], pLc[1]};
    if (slot + 1 < slot1) {
      const bf16_t* ps = Pb + (size_t)csr_src[slot + 1] * 1024;
#pragma unroll
      for (int h = 0; h < 2; h++) {
        int cb = h * 128 + sub * 8;
        eLn[h] = *(const bf16x8*)(ps + cb);
        pLn[h] = *(const bf16x8*)(ps + 512 + cb);
      }
    }
    int dn = csr_dst[slot];
    if (dn != cur_dst) {  // group-uniform branch (slots share dst in runs)
      cur_dst = dn;
      const bf16_t* pd = Pb + (size_t)dn * 1024;
#pragma unroll
      for (int h = 0; h < 2; h++) {
        int cb = h * 128 + sub * 8;
        bf16x8 a = *(const bf16x8*)(pd + 256 + cb);
        bf16x8 p = *(const bf16x8*)(pd + 768 + cb);
        eR[h][0] = cvt_lo(a);
        eR[h][1] = cvt_hi(a);
        pR[h][0] = cvt_lo(p);
        pR[h][1] = cvt_hi(p);
      }
    }
    f32x4 v0 = zero, v1 = zero, v2 = zero;
#pragma unroll
    for (int h = 0; h < 2; h++) {
      f32x4 el0 = cvt_lo(eLc[h]), el1 = cvt_hi(eLc[h]);
      f32x4 pl0 = cvt_lo(pLc[h]), pl1 = cvt_hi(pLc[h]);
      f32x4 he0 = __builtin_elementwise_max(el0 + eR[h][0], zero);
      f32x4 he1 = __builtin_elementwise_max(el1 + eR[h][1], zero);
      f32x4 hp0 = __builtin_elementwise_max(pl0 + pR[h][0], zero);
      f32x4 hp1 = __builtin_elementwise_max(pl1 + pR[h][1], zero);
      v0 += he0 * w_ec[h][0] + he1 * w_ec[h][1];
      v1 += hp0 * w_p0[h][0] + hp1 * w_p0[h][1];
      v2 += hp0 * w_p1[h][0] + hp1 * w_p1[h][1];
    }
    float s0 = v0[0] + v0[1] + v0[2] + v0[3];
    float s1 = v1[0] + v1[1] + v1[2] + v1[3];
    float s2 = v2[0] + v2[1] + v2[2] + v2[3];
#pragma unroll
    for (int mm = 1; mm < 16; mm <<= 1) {
      s0 += __shfl_xor(s0, mm);
      s1 += __shfl_xor(s1, mm);
      s2 += __shfl_xor(s2, mm);
    }
    if (sub == 0) {
      int eid = csr_eid[slot];
      out[eid] = s0 + be;
      float p0 = s1 + bp0;
      float p1 = s2 + bp1;
      // stable softplus = max(x,0) + log1p(exp(-|x|))
      out[(size_t)E + 2 * eid]     = fmaxf(p0, 0.f) + log1pf(__expf(-fabsf(p0)));
      out[(size_t)E + 2 * eid + 1] = fmaxf(p1, 0.f) + log1pf(__expf(-fabsf(p1)));
    }
    eLc[0] = eLn[0]; eLc[1] = eLn[1];
    pLc[0] = pLn[0]; pLc[1] = pLn[1];
  }
}

extern "C" void kernel_launch(void* const* d_in, const int* in_sizes, int n_in,
                              void* d_out, int out_size, void* d_ws, size_t ws_size,
                              hipStream_t stream) {
  const float* x    = (const float*)d_in[0];
  const int*   ei   = (const int*)d_in[1];
  const float* W_in = (const float*)d_in[2];
  const float* b_in = (const float*)d_in[3];
  const float* Wq   = (const float*)d_in[4];
  const float* bq   = (const float*)d_in[5];
  const float* Wk   = (const float*)d_in[6];
  const float* bk   = (const float*)d_in[7];
  const float* Wv   = (const float*)d_in[8];
  const float* bv   = (const float*)d_in[9];
  const float* Ws   = (const float*)d_in[10];
  const float* bs   = (const float*)d_in[11];
  const float* ln_g = (const float*)d_in[12];
  const float* ln_b = (const float*)d_in[13];
  const float* Wec1 = (const float*)d_in[14];
  const float* bec1 = (const float*)d_in[15];
  const float* Wec2 = (const float*)d_in[16];
  const float* bec2 = (const float*)d_in[17];
  const float* Wpp1 = (const float*)d_in[18];
  const float* bpp1 = (const float*)d_in[19];
  const float* Wpp2 = (const float*)d_in[20];
  const float* bpp2 = (const float*)d_in[21];

  const int N = in_sizes[0] / 128;
  const int E = in_sizes[1] / 2;
  const int* srcv = ei;
  const int* dstv = ei + E;
  const int NB = (N + 255) / 256;

  // ---- carve workspace ----
  char* w = (char*)d_ws;
  size_t off = 0;
  auto carve = [&](size_t bytes) -> char* {
    char* p = w + off;
    off = (off + bytes + 255) & ~(size_t)255;
    return p;
  };
  bf16_t* xb      = (bf16_t*)carve((size_t)N * 128 * 2);
  bf16_t* hb      = (bf16_t*)carve((size_t)N * 256 * 2);
  bf16_t* qkvsb   = (bf16_t*)carve((size_t)N * 1024 * 2);  // reused as Pb after layers
  bf16_t* w_in_b  = (bf16_t*)carve((size_t)256 * 128 * 2);
  bf16_t* wqkvs_b = (bf16_t*)carve((size_t)3 * 1024 * 256 * 2);
  float*  bqkvs   = (float*) carve((size_t)3 * 1024 * 4);
  bf16_t* wnode_b = (bf16_t*)carve((size_t)1024 * 256 * 2);
  float*  bnode   = (float*) carve((size_t)1024 * 4);
  int*    counts  = (int*)   carve((size_t)N * 4);
  int*    row_ptr = (int*)   carve((size_t)(N + 1) * 4);
  int*    cursor  = (int*)   carve((size_t)N * 4);
  int*    pre     = (int*)   carve((size_t)N * 4);
  int*    blk     = (int*)   carve((size_t)256 * 4);
  int*    csr_src = (int*)   carve((size_t)E * 4);
  int*    csr_dst = (int*)   carve((size_t)E * 4);
  int*    csr_eid = (int*)   carve((size_t)E * 4);

  hipMemsetAsync(counts, 0, (size_t)N * 4, stream);

  // ---- prep ----
  int n4 = N * 128 / 4;
  k_cvt4<<<dim3((n4 + 255) / 256), dim3(256), 0, stream>>>(x, xb, n4);
  const int PREP_TOT = 256 * 128 + 3 * 1024 * 256 + 1024 * 256 + 3 * 1024 + 1024;
  k_prep_w<<<dim3((PREP_TOT + 255) / 256), dim3(256), 0, stream>>>(
      W_in, Wq, Wk, Wv, Ws, bq, bk, bv, bs, Wec1, Wpp1, bec1, bpp1,
      w_in_b, wqkvs_b, bqkvs, wnode_b, bnode);

  // ---- input projection: h0 = x @ W_in^T + b_in (bf16 residual stream) ----
  k_gemm128<<<dim3(2, (N + 127) / 128), dim3(256), 0, stream>>>(
      xb, w_in_b, b_in, hb, N, 256, 128);

  // ---- CSR build (parallel 3-phase scan) ----
  k_count<<<dim3((E + 255) / 256), dim3(256), 0, stream>>>(dstv, counts, E);
  k_scan_a<<<dim3(NB), dim3(256), 0, stream>>>(counts, pre, blk, N);
  k_scan_b<<<dim3(1), dim3(256), 0, stream>>>(blk, NB);
  k_scan_c<<<dim3(NB), dim3(256), 0, stream>>>(counts, pre, blk, row_ptr, cursor, N);
  k_fill<<<dim3((E + 255) / 256), dim3(256), 0, stream>>>(
      srcv, dstv, cursor, csr_src, csr_dst, csr_eid, E);

  // ---- 3 transformer layers ----
  for (int l = 0; l < 3; ++l) {
    k_gemm128<<<dim3(8, (N + 127) / 128), dim3(256), 0, stream>>>(
        hb, wqkvs_b + (size_t)l * 1024 * 256, bqkvs + l * 1024, qkvsb, N, 1024, 256);
    k_attn_ln<<<dim3((N + 3) / 4), dim3(256), 0, stream>>>(
        qkvsb, row_ptr, csr_src, hb, ln_g + l * 256, ln_b + l * 256, N);
  }

  // ---- edge heads: per-node P tables (into qkvsb, now free), then per-edge finish ----
  k_gemm128<<<dim3(8, (N + 127) / 128), dim3(256), 0, stream>>>(
      hb, wnode_b, bnode, qkvsb, N, 1024, 256);
  int ngroups = (E + EF_SLOTS - 1) / EF_SLOTS;
  k_edge_final<<<dim3((ngroups + 15) / 16), dim3(256), 0, stream>>>(
      qkvsb, csr_src, csr_dst, csr_eid, Wec2, Wpp2, bec2, bpp2, (float*)d_out, E);
}